// Round 6
// baseline (980.967 us; speedup 1.0000x reference)
//
#include <hip/hip_runtime.h>
#include <hip/hip_bf16.h>
#include <stdint.h>
#include <stddef.h>

#define E_ 8
#define C_ 4096
#define H_ 1024
#define I_ 4096

typedef short s16;
typedef __attribute__((ext_vector_type(8))) short short8;   // 8 bf16 (4 VGPRs)
typedef __attribute__((ext_vector_type(4))) float f32x4;    // MFMA C/D frag
typedef __attribute__((ext_vector_type(4))) float float4v;

__device__ __forceinline__ s16 f2bf(float f) {
  union { __hip_bfloat16 h; s16 s; } u;
  u.h = __float2bfloat16(f);
  return u.s;
}

// async global->LDS, 16B per lane. LDS dest is wave-uniform base + lane*16.
__device__ __forceinline__ void gload16(const void* gsrc, void* ldst) {
  __builtin_amdgcn_global_load_lds(
      (const __attribute__((address_space(1))) void*)gsrc,
      (__attribute__((address_space(3))) void*)ldst, 16, 0, 0);
}

// ---------------------------------------------------------------------------
// prep: expert = blockIdx.y
// z=0: x fp32 -> bf16
// z=1: Wg [H][I] -> interleaved Wgu rows (gate block)   [2I][H] bf16
// z=2: Wu [H][I] -> interleaved Wgu rows (up block)
// z=3: Wd [I][H] -> WdT [H][I] bf16
// Interleave: real col i -> row (i&~15)*2 + (i&15) (+16 for up), so a
// standard GEMM on Wgu puts gate/up for the same i in adjacent n-fragments.
// ---------------------------------------------------------------------------
__global__ __launch_bounds__(256) void prep_kernel(
    const float* __restrict__ x, const float* __restrict__ Wg,
    const float* __restrict__ Wu, const float* __restrict__ Wd,
    s16* __restrict__ xb, s16* __restrict__ Wgu, s16* __restrict__ WdT)
{
  __shared__ float tile[64][65];
  const int t = threadIdx.x;
  const int z = blockIdx.z;
  const size_t e = blockIdx.y;

  if (z == 0) {
    size_t base = e * (size_t)C_ * H_ + ((size_t)blockIdx.x * 256 + t) * 16;
    for (int j = 0; j < 16; j += 8) {
      float4v v0 = *(const float4v*)(x + base + j);
      float4v v1 = *(const float4v*)(x + base + j + 4);
      s16 o[8];
      o[0] = f2bf(v0[0]); o[1] = f2bf(v0[1]); o[2] = f2bf(v0[2]); o[3] = f2bf(v0[3]);
      o[4] = f2bf(v1[0]); o[5] = f2bf(v1[1]); o[6] = f2bf(v1[2]); o[7] = f2bf(v1[3]);
      *(short8*)(xb + base + j) = *(short8*)o;
    }
    return;
  }

  const float* src; int Cc;
  if (z == 1)      { src = Wg + e * (size_t)H_ * I_; Cc = I_; }
  else if (z == 2) { src = Wu + e * (size_t)H_ * I_; Cc = I_; }
  else             { src = Wd + e * (size_t)H_ * I_; Cc = H_; }

  const int tpr  = Cc >> 6;
  const int trow = blockIdx.x / tpr;
  const int tcol = blockIdx.x % tpr;

  const int c = t & 63, rq = t >> 6;
  for (int i = 0; i < 16; ++i) {
    int r = rq * 16 + i;
    tile[r][c] = src[(size_t)(trow * 64 + r) * Cc + tcol * 64 + c];
  }
  __syncthreads();

  const int ro = t >> 2, cb = (t & 3) * 16;
  s16 o[16];
  for (int j = 0; j < 16; ++j) o[j] = f2bf(tile[cb + j][ro]);

  const int i0 = tcol * 64 + ro;   // transposed row index
  s16* op;
  if (z == 3) {
    op = WdT + e * (size_t)H_ * I_ + (size_t)i0 * I_ + trow * 64 + cb;
  } else {
    int grow = ((i0 & ~15) << 1) + (i0 & 15) + ((z == 2) ? 16 : 0);
    op = Wgu + e * (size_t)2 * I_ * H_ + (size_t)grow * H_ + trow * 64 + cb;
  }
  *(short8*)op       = *(short8*)&o[0];
  *(short8*)(op + 8) = *(short8*)&o[8];
}

// ---------------------------------------------------------------------------
// 256x256-tile 8-phase GEMM (m201-style template) with MULTI-TILE blocks:
// each block computes NTILES consecutive bn-tiles (same bm -> same A panel),
// K-pipeline runs continuously across sub-tile boundaries via a virtual tile
// index v (staging of the next panel's first tiles issues during the last
// iterations of the previous sub-tile; no drain, no re-prime). Per-sub-tile
// epilogue stores interpose in the vmem stream; vmcnt drains oldest-first so
// the counted ledger stays correct.
// A [e][C_][K] bf16 (K contiguous), B [e][NB][K] bf16 (K contiguous).
// GATEUP: K=1024, NB=8192 (interleaved Wgu), out = silu(g)*u -> bf16 [e][C_][I_]
// !GATEUP: K=4096, NB=1024 (WdT),             out = fp32 [e][C_][H_]
// 512 thr = 8 waves (2M x 4N); per-wave 128x64; LDS 128 KiB dbuf (1 block/CU).
// T2: LDS linear (gload_lds), source col pre-swizzled with col^=(row&7)<<3;
// ds_read applies the same XOR.  T4: single vmcnt(4) per K-tile (ph4/ph8).
// ---------------------------------------------------------------------------
#define LDAF(B, MH, M, CX) \
  (*(const short8*)(shm + (B)*16384 + ((wm + (MH)*64 + (M)*16 + lr) << 6) + (CX)))
#define LDBF(B, N, CX) \
  (*(const short8*)(shm + 32768 + (B)*16384 + ((wn + (N)*16 + lr) << 6) + (CX)))

#define MFMA16(MH, A0, A1, A2, A3)                                                            \
  acc[(MH)*4+0][0] = __builtin_amdgcn_mfma_f32_16x16x32_bf16(A0, bf[0], acc[(MH)*4+0][0],0,0,0); \
  acc[(MH)*4+0][1] = __builtin_amdgcn_mfma_f32_16x16x32_bf16(A0, bf[1], acc[(MH)*4+0][1],0,0,0); \
  acc[(MH)*4+0][2] = __builtin_amdgcn_mfma_f32_16x16x32_bf16(A0, bf[2], acc[(MH)*4+0][2],0,0,0); \
  acc[(MH)*4+0][3] = __builtin_amdgcn_mfma_f32_16x16x32_bf16(A0, bf[3], acc[(MH)*4+0][3],0,0,0); \
  acc[(MH)*4+1][0] = __builtin_amdgcn_mfma_f32_16x16x32_bf16(A1, bf[0], acc[(MH)*4+1][0],0,0,0); \
  acc[(MH)*4+1][1] = __builtin_amdgcn_mfma_f32_16x16x32_bf16(A1, bf[1], acc[(MH)*4+1][1],0,0,0); \
  acc[(MH)*4+1][2] = __builtin_amdgcn_mfma_f32_16x16x32_bf16(A1, bf[2], acc[(MH)*4+1][2],0,0,0); \
  acc[(MH)*4+1][3] = __builtin_amdgcn_mfma_f32_16x16x32_bf16(A1, bf[3], acc[(MH)*4+1][3],0,0,0); \
  acc[(MH)*4+2][0] = __builtin_amdgcn_mfma_f32_16x16x32_bf16(A2, bf[0], acc[(MH)*4+2][0],0,0,0); \
  acc[(MH)*4+2][1] = __builtin_amdgcn_mfma_f32_16x16x32_bf16(A2, bf[1], acc[(MH)*4+2][1],0,0,0); \
  acc[(MH)*4+2][2] = __builtin_amdgcn_mfma_f32_16x16x32_bf16(A2, bf[2], acc[(MH)*4+2][2],0,0,0); \
  acc[(MH)*4+2][3] = __builtin_amdgcn_mfma_f32_16x16x32_bf16(A2, bf[3], acc[(MH)*4+2][3],0,0,0); \
  acc[(MH)*4+3][0] = __builtin_amdgcn_mfma_f32_16x16x32_bf16(A3, bf[0], acc[(MH)*4+3][0],0,0,0); \
  acc[(MH)*4+3][1] = __builtin_amdgcn_mfma_f32_16x16x32_bf16(A3, bf[1], acc[(MH)*4+3][1],0,0,0); \
  acc[(MH)*4+3][2] = __builtin_amdgcn_mfma_f32_16x16x32_bf16(A3, bf[2], acc[(MH)*4+3][2],0,0,0); \
  acc[(MH)*4+3][3] = __builtin_amdgcn_mfma_f32_16x16x32_bf16(A3, bf[3], acc[(MH)*4+3][3],0,0,0);

#define VMW4 asm volatile("s_waitcnt vmcnt(4)" ::: "memory");

#define PHASE(B, MH, CX, RDB, STMT, WV)                                      \
  {                                                                          \
    short8 af0 = LDAF(B, MH, 0, CX);                                         \
    short8 af1 = LDAF(B, MH, 1, CX);                                         \
    short8 af2 = LDAF(B, MH, 2, CX);                                         \
    short8 af3 = LDAF(B, MH, 3, CX);                                         \
    if (RDB) {                                                               \
      bf[0] = LDBF(B, 0, CX); bf[1] = LDBF(B, 1, CX);                        \
      bf[2] = LDBF(B, 2, CX); bf[3] = LDBF(B, 3, CX);                        \
    }                                                                        \
    STMT                                                                     \
    __builtin_amdgcn_sched_barrier(0);                                       \
    __builtin_amdgcn_s_barrier();                                            \
    asm volatile("s_waitcnt lgkmcnt(0)" ::: "memory");                       \
    __builtin_amdgcn_sched_barrier(0);                                       \
    __builtin_amdgcn_s_setprio(1);                                           \
    MFMA16(MH, af0, af1, af2, af3)                                           \
    __builtin_amdgcn_s_setprio(0);                                           \
    __builtin_amdgcn_sched_barrier(0);                                       \
    WV                                                                       \
    __builtin_amdgcn_s_barrier();                                            \
  }

template<bool GATEUP, int NTILES>
__global__ __launch_bounds__(512, 2) void gemm256(
    const s16* __restrict__ Abase, const s16* __restrict__ Bbase,
    s16* __restrict__ HOut, float* __restrict__ FOut)
{
  constexpr int K     = GATEUP ? H_ : I_;
  constexpr int NB    = GATEUP ? 2 * I_ : H_;
  constexpr int NT    = K / 64;               // K-tiles per sub-tile
  constexpr int LOGNT = GATEUP ? 4 : 6;       // log2(NT)
  constexpr int TN    = NB / 256;
  constexpr int TNC   = TN / NTILES;          // bn chunks
  constexpr int TM    = C_ / 256;
  constexpr int VMAX  = NTILES * NT - 1;      // last virtual K-tile

  __shared__ s16 shm[65536];                  // 128 KiB: A dbuf 64K | B dbuf 64K

  const int tid  = threadIdx.x;
  const int wave = tid >> 6, lane = tid & 63;
  const int e    = blockIdx.z;

  // Block->chunk mapping. gridX % 8 == 0, so (bid & 7) is XCD-stable.
  const int bid = blockIdx.x;
  int bm, bnc;
  if constexpr (GATEUP) {
    // Per-XCD: 2 bn-chunks x 8 bm (B live set 2 chunks x 2 MiB = 4 MiB = L2).
    const int xcd = bid & 7;
    const int idx = bid >> 3;                 // 0..15
    bnc = (xcd & 3) * 2 + (idx & 1);
    bm  = (xcd >> 2) * 8 + (idx >> 1);
  } else {
    // down: plain bijective XCD swizzle over the 32-chunk grid.
    const int swz = (bid & 7) * ((TM * TNC) / 8) + (bid >> 3);
    bm = swz / TNC; bnc = swz % TNC;
  }

  const s16* A  = Abase + (size_t)e * C_ * K + (size_t)bm * 256 * K;
  const s16* B0 = Bbase + (size_t)e * NB * K + (size_t)bnc * NTILES * 256 * K;

  const int wm  = (wave >> 2) * 128;
  const int wn  = (wave & 3) * 64;
  const int lr  = lane & 15;
  const int lkb = (lane >> 4) * 8;
  const int xr  = (lr & 7) << 3;              // T2 read-side XOR
  const int cx0 = lkb ^ xr;                   // kk=0 col (elements)
  const int cx1 = (32 + lkb) ^ xr;            // kk=1

  // staging: thread tid covers row (h*128 + l*64 + tid>>3), swizzled col
  const int srow = tid >> 3;
  const int scol = ((tid & 7) ^ (srow & 7)) * 8;   // T2 write-side (source) XOR
  const size_t stoff = (size_t)srow * K + scol;
  const int sdst = wave * 512;                // wave-uniform LDS slot (elements)

  // virtual tile index v in [0, NTILES*NT): sub-tile j = v>>LOGNT, kt = v&(NT-1)
  auto stageA = [&](int v, int b) {
    const int kt = v & (NT - 1);
    #pragma unroll
    for (int h = 0; h < 2; ++h)
      #pragma unroll
      for (int l = 0; l < 2; ++l)
        gload16(A + (size_t)(h * 128 + l * 64) * K + (size_t)kt * 64 + stoff,
                shm + b * 16384 + h * 8192 + l * 4096 + sdst);
  };
  auto stageB = [&](int v, int b) {
    const int jb = v >> LOGNT;
    const int kt = v & (NT - 1);
    const s16* Bp = B0 + (size_t)jb * (256 * K);
    #pragma unroll
    for (int h = 0; h < 2; ++h)
      #pragma unroll
      for (int l = 0; l < 2; ++l)
        gload16(Bp + (size_t)(h * 128 + l * 64) * K + (size_t)kt * 64 + stoff,
                shm + 32768 + b * 16384 + h * 8192 + l * 4096 + sdst);
  };

  f32x4 acc[8][4];
  #pragma unroll
  for (int m = 0; m < 8; ++m)
    #pragma unroll
    for (int n = 0; n < 4; ++n) acc[m][n] = (f32x4){0.f, 0.f, 0.f, 0.f};

  // prologue: tile0 (buf0) fully + tile1.B (buf1); leave t1.B in flight
  stageB(0, 0);
  stageA(0, 0);
  stageB(1, 1);
  asm volatile("s_waitcnt vmcnt(4)" ::: "memory");
  __builtin_amdgcn_sched_barrier(0);
  __builtin_amdgcn_s_barrier();

  short8 bf[4];
  const int lq = (lane >> 4) * 4;

  // vmcnt ledger (per iteration, virtual index v): issue (v+1).A(ph1)
  // (v+2).B(ph4) (v+2).A(ph5) (v+3).B(ph8); vmcnt(4) at ph4 -> v+1 complete
  // before ph5 reads buf1; vmcnt(4) at ph8 -> v+2 complete before next ph1
  // reads buf0. Buffer parity = v&1 everywhere, consistent across sub-tile
  // boundaries. Epilogue stores are older than all subsequent loads, so the
  // counted waits drain them first (correct; at worst a short extra wait).
  for (int j = 0; j < NTILES; ++j) {
    for (int ii = 0; ii < NT / 2; ++ii) {
      const int v  = j * NT + 2 * ii;
      const int t1 = v + 1;
      const int t2 = (v + 2 <= VMAX) ? v + 2 : VMAX;
      const int t3 = (v + 3 <= VMAX) ? v + 3 : VMAX;
      PHASE(0, 0, cx0, 1, { stageA(t1, 1); }, )
      PHASE(0, 1, cx0, 0, {}, )
      PHASE(0, 0, cx1, 1, {}, )
      PHASE(0, 1, cx1, 0, { stageB(t2, 0); }, VMW4)
      PHASE(1, 0, cx0, 1, { stageA(t2, 0); }, )
      PHASE(1, 1, cx0, 0, {}, )
      PHASE(1, 0, cx1, 1, {}, )
      PHASE(1, 1, cx1, 0, { stageB(t3, 1); }, VMW4)
    }

    // ---- epilogue for sub-tile j (no LDS, no barriers) ----
    const int bn = bnc * NTILES + j;
    if constexpr (GATEUP) {
      s16* Hp = HOut + (size_t)e * C_ * I_;
      const int ibase = bn * 128 + (wn >> 1);
      #pragma unroll
      for (int m = 0; m < 8; ++m) {
        const int row = bm * 256 + wm + m * 16 + lq;
        #pragma unroll
        for (int p = 0; p < 2; ++p) {
          const int col = ibase + p * 16 + lr;
          s16* hp = Hp + (size_t)row * I_ + col;
          #pragma unroll
          for (int q = 0; q < 4; ++q) {
            float g = acc[m][2 * p][q], u = acc[m][2 * p + 1][q];
            float sg = 1.0f / (1.0f + __expf(-g));
            hp[(size_t)q * I_] = f2bf(g * sg * u);
          }
        }
      }
    } else {
      float* Op = FOut + (size_t)e * C_ * H_;
      #pragma unroll
      for (int m = 0; m < 8; ++m) {
        const int row = bm * 256 + wm + m * 16 + lq;
        #pragma unroll
        for (int n = 0; n < 4; ++n) {
          const int col = bn * 256 + wn + n * 16 + lr;
          #pragma unroll
          for (int q = 0; q < 4; ++q)
            Op[(size_t)(row + q) * H_ + col] = acc[m][n][q];
        }
      }
    }
    if (j + 1 < NTILES) {
      #pragma unroll
      for (int m = 0; m < 8; ++m)
        #pragma unroll
        for (int n = 0; n < 4; ++n) acc[m][n] = (f32x4){0.f, 0.f, 0.f, 0.f};
    }
  }
}

// ---------------------------------------------------------------------------
extern "C" void kernel_launch(void* const* d_in, const int* in_sizes, int n_in,
                              void* d_out, int out_size, void* d_ws, size_t ws_size,
                              hipStream_t stream) {
  const float* x  = (const float*)d_in[0];
  const float* Wg = (const float*)d_in[1];
  const float* Wu = (const float*)d_in[2];
  const float* Wd = (const float*)d_in[3];
  float* out = (float*)d_out;

  const size_t szX  = (size_t)C_ * H_;
  const size_t szGU = (size_t)2 * I_ * H_;
  const size_t szWd = (size_t)H_ * I_;
  const size_t szH  = (size_t)C_ * I_;

  const size_t needFull = 2 * E_ * (szX + szGU + szWd + szH);   // 512 MiB

  // grids: gateup 16bm x 8chunks = 128 blocks; down 16bm x 2chunks = 32
  constexpr int GU_BLK = (C_ / 256) * ((2 * I_ / 256) / 4);
  constexpr int DN_BLK = (C_ / 256) * ((H_ / 256) / 2);

  if (ws_size >= needFull) {
    s16* xb  = (s16*)d_ws;                  // [E][C][H]
    s16* Wgu = xb  + E_ * szX;              // [E][2I][H] interleaved
    s16* WdT = Wgu + E_ * szGU;             // [E][H][I]
    s16* hbf = WdT + E_ * szWd;             // [E][C][I]

    prep_kernel<<<dim3(1024, E_, 4), 256, 0, stream>>>(
        x, Wg, Wu, Wd, xb, Wgu, WdT);
    gemm256<true, 4><<<dim3(GU_BLK, 1, E_), 512, 0, stream>>>(
        xb, Wgu, hbf, nullptr);
    gemm256<false, 2><<<dim3(DN_BLK, 1, E_), 512, 0, stream>>>(
        hbf, WdT, nullptr, out);
  } else {
    // per-expert fallback (67 MiB workspace), same kernels with gridZ=1
    s16* xb  = (s16*)d_ws;
    s16* Wgu = xb  + szX;
    s16* WdT = Wgu + szGU;
    s16* hbf = WdT + szWd;

    for (int e = 0; e < E_; ++e) {
      prep_kernel<<<dim3(1024, 1, 4), 256, 0, stream>>>(
          x + e * szX, Wg + e * szWd, Wu + e * szWd, Wd + e * szWd,
          xb, Wgu, WdT);
      gemm256<true, 4><<<dim3(GU_BLK, 1, 1), 512, 0, stream>>>(
          xb, Wgu, hbf, nullptr);
      gemm256<false, 2><<<dim3(DN_BLK, 1, 1), 512, 0, stream>>>(
          hbf, WdT, nullptr, out + e * szX);
    }
  }
}

// Round 7
// 951.862 us; speedup vs baseline: 1.0306x; 1.0306x over previous
//
#include <hip/hip_runtime.h>
#include <hip/hip_bf16.h>
#include <stdint.h>
#include <stddef.h>

#define E_ 8
#define C_ 4096
#define H_ 1024
#define I_ 4096

typedef short s16;
typedef __attribute__((ext_vector_type(8))) short short8;   // 8 bf16 (4 VGPRs)
typedef __attribute__((ext_vector_type(4))) short short4v;  // 4 bf16 (8B)
typedef __attribute__((ext_vector_type(4))) float f32x4;    // MFMA C/D frag
typedef __attribute__((ext_vector_type(4))) float float4v;

__device__ __forceinline__ s16 f2bf(float f) {
  union { __hip_bfloat16 h; s16 s; } u;
  u.h = __float2bfloat16(f);
  return u.s;
}

// async global->LDS, 16B per lane. LDS dest is wave-uniform base + lane*16.
__device__ __forceinline__ void gload16(const void* gsrc, void* ldst) {
  __builtin_amdgcn_global_load_lds(
      (const __attribute__((address_space(1))) void*)gsrc,
      (__attribute__((address_space(3))) void*)ldst, 16, 0, 0);
}

// ---------------------------------------------------------------------------
// prep: expert = blockIdx.y
// z=0: x fp32 -> bf16
// z=1: Wg [H][I] -> interleaved Wgu rows (gate block)   [2I][H] bf16
// z=2: Wu [H][I] -> interleaved Wgu rows (up block)
// z=3: Wd [I][H] -> WdT [H][I] bf16
// Interleave: real col i -> row (i&~15)*2 + (i&15) (+16 for up), so a
// standard GEMM on Wgu puts gate/up for the same i in adjacent n-fragments.
// ---------------------------------------------------------------------------
__global__ __launch_bounds__(256) void prep_kernel(
    const float* __restrict__ x, const float* __restrict__ Wg,
    const float* __restrict__ Wu, const float* __restrict__ Wd,
    s16* __restrict__ xb, s16* __restrict__ Wgu, s16* __restrict__ WdT)
{
  __shared__ float tile[64][65];
  const int t = threadIdx.x;
  const int z = blockIdx.z;
  const size_t e = blockIdx.y;

  if (z == 0) {
    size_t base = e * (size_t)C_ * H_ + ((size_t)blockIdx.x * 256 + t) * 16;
    for (int j = 0; j < 16; j += 8) {
      float4v v0 = *(const float4v*)(x + base + j);
      float4v v1 = *(const float4v*)(x + base + j + 4);
      s16 o[8];
      o[0] = f2bf(v0[0]); o[1] = f2bf(v0[1]); o[2] = f2bf(v0[2]); o[3] = f2bf(v0[3]);
      o[4] = f2bf(v1[0]); o[5] = f2bf(v1[1]); o[6] = f2bf(v1[2]); o[7] = f2bf(v1[3]);
      *(short8*)(xb + base + j) = *(short8*)o;
    }
    return;
  }

  const float* src; int Cc;
  if (z == 1)      { src = Wg + e * (size_t)H_ * I_; Cc = I_; }
  else if (z == 2) { src = Wu + e * (size_t)H_ * I_; Cc = I_; }
  else             { src = Wd + e * (size_t)H_ * I_; Cc = H_; }

  const int tpr  = Cc >> 6;
  const int trow = blockIdx.x / tpr;
  const int tcol = blockIdx.x % tpr;

  const int c = t & 63, rq = t >> 6;
  for (int i = 0; i < 16; ++i) {
    int r = rq * 16 + i;
    tile[r][c] = src[(size_t)(trow * 64 + r) * Cc + tcol * 64 + c];
  }
  __syncthreads();

  const int ro = t >> 2, cb = (t & 3) * 16;
  s16 o[16];
  for (int j = 0; j < 16; ++j) o[j] = f2bf(tile[cb + j][ro]);

  const int i0 = tcol * 64 + ro;   // transposed row index
  s16* op;
  if (z == 3) {
    op = WdT + e * (size_t)H_ * I_ + (size_t)i0 * I_ + trow * 64 + cb;
  } else {
    int grow = ((i0 & ~15) << 1) + (i0 & 15) + ((z == 2) ? 16 : 0);
    op = Wgu + e * (size_t)2 * I_ * H_ + (size_t)grow * H_ + trow * 64 + cb;
  }
  *(short8*)op       = *(short8*)&o[0];
  *(short8*)(op + 8) = *(short8*)&o[8];
}

// ---------------------------------------------------------------------------
// 256x256-tile 8-phase GEMM (m201-style template), SWAPPED MFMA operands:
// acc[m][n] = mfma(bf[n], af[m], acc) -> D is transposed vs the standard
// layout, so each lane holds 4 CONSECUTIVE COLUMNS of one output row:
//   row = ...+ m*16 + (lane&15),  col = ...+ n*16 + (lane>>4)*4 + q
// -> epilogue stores become 8B (bf16 x4) / 16B (f32 x4) vector stores,
// 4x fewer store instructions (this was the measured ~49k-cyc per-tile
// fixed cost F; steady-state loop already runs at ~89% MFMA util).
// Valid because A and B fragments have identical lane->(row,k) maps.
// A [e][C_][K] bf16 (K contiguous), B [e][NB][K] bf16 (K contiguous).
// GATEUP: K=1024, NB=8192 (interleaved Wgu), out = silu(g)*u -> bf16 [e][C_][I_]
// !GATEUP: K=4096, NB=1024 (WdT),             out = fp32 [e][C_][H_]
// 512 thr = 8 waves (2M x 4N); per-wave 128x64; LDS 128 KiB dbuf (1 block/CU).
// T2: LDS linear (gload_lds), source col pre-swizzled with col^=(row&7)<<3;
// ds_read applies the same XOR.  T4: single vmcnt(4) per K-tile (ph4/ph8).
// ---------------------------------------------------------------------------
#define LDAF(B, MH, M, CX) \
  (*(const short8*)(shm + (B)*16384 + ((wm + (MH)*64 + (M)*16 + lr) << 6) + (CX)))
#define LDBF(B, N, CX) \
  (*(const short8*)(shm + 32768 + (B)*16384 + ((wn + (N)*16 + lr) << 6) + (CX)))

// swapped operand order: D^T layout (see header comment)
#define MFMA16(MH, A0, A1, A2, A3)                                                            \
  acc[(MH)*4+0][0] = __builtin_amdgcn_mfma_f32_16x16x32_bf16(bf[0], A0, acc[(MH)*4+0][0],0,0,0); \
  acc[(MH)*4+0][1] = __builtin_amdgcn_mfma_f32_16x16x32_bf16(bf[1], A0, acc[(MH)*4+0][1],0,0,0); \
  acc[(MH)*4+0][2] = __builtin_amdgcn_mfma_f32_16x16x32_bf16(bf[2], A0, acc[(MH)*4+0][2],0,0,0); \
  acc[(MH)*4+0][3] = __builtin_amdgcn_mfma_f32_16x16x32_bf16(bf[3], A0, acc[(MH)*4+0][3],0,0,0); \
  acc[(MH)*4+1][0] = __builtin_amdgcn_mfma_f32_16x16x32_bf16(bf[0], A1, acc[(MH)*4+1][0],0,0,0); \
  acc[(MH)*4+1][1] = __builtin_amdgcn_mfma_f32_16x16x32_bf16(bf[1], A1, acc[(MH)*4+1][1],0,0,0); \
  acc[(MH)*4+1][2] = __builtin_amdgcn_mfma_f32_16x16x32_bf16(bf[2], A1, acc[(MH)*4+1][2],0,0,0); \
  acc[(MH)*4+1][3] = __builtin_amdgcn_mfma_f32_16x16x32_bf16(bf[3], A1, acc[(MH)*4+1][3],0,0,0); \
  acc[(MH)*4+2][0] = __builtin_amdgcn_mfma_f32_16x16x32_bf16(bf[0], A2, acc[(MH)*4+2][0],0,0,0); \
  acc[(MH)*4+2][1] = __builtin_amdgcn_mfma_f32_16x16x32_bf16(bf[1], A2, acc[(MH)*4+2][1],0,0,0); \
  acc[(MH)*4+2][2] = __builtin_amdgcn_mfma_f32_16x16x32_bf16(bf[2], A2, acc[(MH)*4+2][2],0,0,0); \
  acc[(MH)*4+2][3] = __builtin_amdgcn_mfma_f32_16x16x32_bf16(bf[3], A2, acc[(MH)*4+2][3],0,0,0); \
  acc[(MH)*4+3][0] = __builtin_amdgcn_mfma_f32_16x16x32_bf16(bf[0], A3, acc[(MH)*4+3][0],0,0,0); \
  acc[(MH)*4+3][1] = __builtin_amdgcn_mfma_f32_16x16x32_bf16(bf[1], A3, acc[(MH)*4+3][1],0,0,0); \
  acc[(MH)*4+3][2] = __builtin_amdgcn_mfma_f32_16x16x32_bf16(bf[2], A3, acc[(MH)*4+3][2],0,0,0); \
  acc[(MH)*4+3][3] = __builtin_amdgcn_mfma_f32_16x16x32_bf16(bf[3], A3, acc[(MH)*4+3][3],0,0,0);

#define VMW4 asm volatile("s_waitcnt vmcnt(4)" ::: "memory");

#define PHASE(B, MH, CX, RDB, STMT, WV)                                      \
  {                                                                          \
    short8 af0 = LDAF(B, MH, 0, CX);                                         \
    short8 af1 = LDAF(B, MH, 1, CX);                                         \
    short8 af2 = LDAF(B, MH, 2, CX);                                         \
    short8 af3 = LDAF(B, MH, 3, CX);                                         \
    if (RDB) {                                                               \
      bf[0] = LDBF(B, 0, CX); bf[1] = LDBF(B, 1, CX);                        \
      bf[2] = LDBF(B, 2, CX); bf[3] = LDBF(B, 3, CX);                        \
    }                                                                        \
    STMT                                                                     \
    __builtin_amdgcn_sched_barrier(0);                                       \
    __builtin_amdgcn_s_barrier();                                            \
    asm volatile("s_waitcnt lgkmcnt(0)" ::: "memory");                       \
    __builtin_amdgcn_sched_barrier(0);                                       \
    __builtin_amdgcn_s_setprio(1);                                           \
    MFMA16(MH, af0, af1, af2, af3)                                           \
    __builtin_amdgcn_s_setprio(0);                                           \
    __builtin_amdgcn_sched_barrier(0);                                       \
    WV                                                                       \
    __builtin_amdgcn_s_barrier();                                            \
  }

template<bool GATEUP>
__global__ __launch_bounds__(512, 2) void gemm256(
    const s16* __restrict__ Abase, const s16* __restrict__ Bbase,
    s16* __restrict__ HOut, float* __restrict__ FOut)
{
  constexpr int K  = GATEUP ? H_ : I_;
  constexpr int NB = GATEUP ? 2 * I_ : H_;
  constexpr int NT = K / 64;                 // K-tiles
  constexpr int TN = NB / 256;
  constexpr int TM = C_ / 256;
  constexpr int NWG = TM * TN;               // % 8 == 0 for both

  __shared__ s16 shm[65536];                 // 128 KiB: A dbuf 64K | B dbuf 64K

  const int tid  = threadIdx.x;
  const int wave = tid >> 6, lane = tid & 63;
  const int e    = blockIdx.z;

  // Block->tile mapping. gridX % 8 == 0, so (bid & 7) is XCD-stable across z.
  const int bid = blockIdx.x;
  int bm, bn;
  if constexpr (GATEUP) {
    // Fetch-optimal per-XCD partition: each XCD owns an 8bn x 8bm sub-grid
    // (cg = xcd&3 picks bn octet, rg = xcd>>2 picks bm octet), bn-inner order.
    const int xcd = bid & 7;
    const int idx = bid >> 3;                // 0..63
    bn = (xcd & 3) * 8 + (idx & 7);
    bm = (xcd >> 2) * 8 + (idx >> 3);
  } else {
    // down: keep the plain bijective XCD swizzle.
    const int swz = (bid & 7) * (NWG / 8) + (bid >> 3);
    bm = swz / TN; bn = swz % TN;
  }

  const s16* A = Abase + (size_t)e * C_ * K + (size_t)bm * 256 * K;
  const s16* B = Bbase + (size_t)e * NB * K + (size_t)bn * 256 * K;

  const int wm  = (wave >> 2) * 128;
  const int wn  = (wave & 3) * 64;
  const int lr  = lane & 15;
  const int lkb = (lane >> 4) * 8;
  const int xr  = (lr & 7) << 3;             // T2 read-side XOR
  const int cx0 = lkb ^ xr;                  // kk=0 col (elements)
  const int cx1 = (32 + lkb) ^ xr;           // kk=1

  // staging: thread tid covers row (h*128 + l*64 + tid>>3), swizzled col
  const int srow = tid >> 3;
  const int scol = ((tid & 7) ^ (srow & 7)) * 8;   // T2 write-side (source) XOR
  const size_t stoff = (size_t)srow * K + scol;
  const int sdst = wave * 512;               // wave-uniform LDS slot (elements)

  auto stageA = [&](int kt, int b) {
    #pragma unroll
    for (int h = 0; h < 2; ++h)
      #pragma unroll
      for (int l = 0; l < 2; ++l)
        gload16(A + (size_t)(h * 128 + l * 64) * K + (size_t)kt * 64 + stoff,
                shm + b * 16384 + h * 8192 + l * 4096 + sdst);
  };
  auto stageB = [&](int kt, int b) {
    #pragma unroll
    for (int h = 0; h < 2; ++h)
      #pragma unroll
      for (int l = 0; l < 2; ++l)
        gload16(B + (size_t)(h * 128 + l * 64) * K + (size_t)kt * 64 + stoff,
                shm + 32768 + b * 16384 + h * 8192 + l * 4096 + sdst);
  };

  f32x4 acc[8][4];
  #pragma unroll
  for (int m = 0; m < 8; ++m)
    #pragma unroll
    for (int n = 0; n < 4; ++n) acc[m][n] = (f32x4){0.f, 0.f, 0.f, 0.f};

  // prologue: tile0 (buf0) fully + tile1.B (buf1); leave t1.B in flight
  stageB(0, 0);
  stageA(0, 0);
  stageB(1, 1);
  asm volatile("s_waitcnt vmcnt(4)" ::: "memory");
  __builtin_amdgcn_sched_barrier(0);
  __builtin_amdgcn_s_barrier();

  short8 bf[4];
  // vmcnt ledger (unchanged from r3/r4): issue t1.A(ph1) t2.B(ph4) t2.A(ph5)
  // t3.B(ph8); vmcnt(4) at ph4 -> t1 complete before ph5 reads buf1;
  // vmcnt(4) at ph8 -> t2 complete before next ph1 reads buf0.
  for (int i = 0; i < NT / 2; ++i) {
    const int t1 = 2 * i + 1;
    const int t2 = (2 * i + 2 < NT) ? (2 * i + 2) : (NT - 1);
    const int t3 = (2 * i + 3 < NT) ? (2 * i + 3) : (NT - 1);
    PHASE(0, 0, cx0, 1, { stageA(t1, 1); }, )
    PHASE(0, 1, cx0, 0, {}, )
    PHASE(0, 0, cx1, 1, {}, )
    PHASE(0, 1, cx1, 0, { stageB(t2, 0); }, VMW4)
    PHASE(1, 0, cx0, 1, { stageA(t2, 0); }, )
    PHASE(1, 1, cx0, 0, {}, )
    PHASE(1, 0, cx1, 1, {}, )
    PHASE(1, 1, cx1, 0, { stageB(t3, 1); }, VMW4)
  }

  // epilogue (swapped-D layout): row = m*16 + (lane&15),
  // col = n*16 + (lane>>4)*4 + q with q=0..3 consecutive -> vector stores.
  const int lcc = (lane >> 4) * 4;
  if constexpr (GATEUP) {
    s16* Hp = HOut + (size_t)e * C_ * I_;
    const int ibase = bn * 128 + (wn >> 1);
    #pragma unroll
    for (int m = 0; m < 8; ++m) {
      const int row = bm * 256 + wm + m * 16 + lr;
      #pragma unroll
      for (int p = 0; p < 2; ++p) {
        const int col = ibase + p * 16 + lcc;   // real i, 4 consecutive
        s16 o4[4];
        #pragma unroll
        for (int q = 0; q < 4; ++q) {
          float g = acc[m][2 * p][q], u = acc[m][2 * p + 1][q];
          float sg = 1.0f / (1.0f + __expf(-g));
          o4[q] = f2bf(g * sg * u);
        }
        *(short4v*)(Hp + (size_t)row * I_ + col) = *(short4v*)o4;
      }
    }
  } else {
    float* Op = FOut + (size_t)e * C_ * H_;
    #pragma unroll
    for (int m = 0; m < 8; ++m) {
      const int row = bm * 256 + wm + m * 16 + lr;
      #pragma unroll
      for (int n = 0; n < 4; ++n) {
        const int col = bn * 256 + wn + n * 16 + lcc;  // 4 consecutive
        *(float4v*)(Op + (size_t)row * H_ + col) = acc[m][n];
      }
    }
  }
}

// ---------------------------------------------------------------------------
extern "C" void kernel_launch(void* const* d_in, const int* in_sizes, int n_in,
                              void* d_out, int out_size, void* d_ws, size_t ws_size,
                              hipStream_t stream) {
  const float* x  = (const float*)d_in[0];
  const float* Wg = (const float*)d_in[1];
  const float* Wu = (const float*)d_in[2];
  const float* Wd = (const float*)d_in[3];
  float* out = (float*)d_out;

  const size_t szX  = (size_t)C_ * H_;
  const size_t szGU = (size_t)2 * I_ * H_;
  const size_t szWd = (size_t)H_ * I_;
  const size_t szH  = (size_t)C_ * I_;

  const size_t needFull = 2 * E_ * (szX + szGU + szWd + szH);   // 512 MiB

  if (ws_size >= needFull) {
    s16* xb  = (s16*)d_ws;                  // [E][C][H]
    s16* Wgu = xb  + E_ * szX;              // [E][2I][H] interleaved
    s16* WdT = Wgu + E_ * szGU;             // [E][H][I]
    s16* hbf = WdT + E_ * szWd;             // [E][C][I]

    prep_kernel<<<dim3(1024, E_, 4), 256, 0, stream>>>(
        x, Wg, Wu, Wd, xb, Wgu, WdT);
    gemm256<true><<<dim3((C_/256)*(2*I_/256), 1, E_), 512, 0, stream>>>(
        xb, Wgu, hbf, nullptr);
    gemm256<false><<<dim3((C_/256)*(H_/256), 1, E_), 512, 0, stream>>>(
        hbf, WdT, nullptr, out);
  } else {
    // per-expert fallback (67 MiB workspace), same kernels with gridZ=1
    s16* xb  = (s16*)d_ws;
    s16* Wgu = xb  + szX;
    s16* WdT = Wgu + szGU;
    s16* hbf = WdT + szWd;

    for (int e = 0; e < E_; ++e) {
      prep_kernel<<<dim3(1024, 1, 4), 256, 0, stream>>>(
          x + e * szX, Wg + e * szWd, Wu + e * szWd, Wd + e * szWd,
          xb, Wgu, WdT);
      gemm256<true><<<dim3((C_/256)*(2*I_/256), 1, 1), 512, 0, stream>>>(
          xb, Wgu, hbf, nullptr);
      gemm256<false><<<dim3((C_/256)*(H_/256), 1, 1), 512, 0, stream>>>(
          hbf, WdT, nullptr, out + e * szX);
    }
  }
}